// Round 1
// 485.069 us; speedup vs baseline: 1.1196x; 1.1196x over previous
//
#include <hip/hip_runtime.h>

typedef _Float16 half_t;
typedef __attribute__((ext_vector_type(8))) _Float16 half8;
typedef __attribute__((ext_vector_type(4))) float floatx4;

// ---------------------------------------------------------------------------
// Round 5: (a) split-K partials via plain stores (no atomics, no memset),
// summed inside bn_stats / bn_relu_pool; (b) B staged with global_load_lds
// (16B) from a pre-swizzled packed weight layout [KIT][OUT][64] so the linear
// LDS write lands in the XOR-swizzled position (source perm == read perm).
// A[pix][k], k = j*IN + i (j-major): j<8 RBF(exp2), j==8 silu.
// ---------------------------------------------------------------------------

#define RBF_SCALE 2.1019644f   // 1.75 * sqrt(log2(e))

// ---- patch gather + LayerNorm -> pn' (fp16, pre-scaled), silu (fp16) ----
template<int C, int H, int W>
__global__ __launch_bounds__(256)
void ln_prep(const float* __restrict__ x,
             const float* __restrict__ lnw, const float* __restrict__ lnb,
             half_t* __restrict__ pn, half_t* __restrict__ sp)
{
    const int HW = H * W, IN = C * 9;
    const int NL = (IN + 63) / 64;
    const int wv = threadIdx.x >> 6, lane = threadIdx.x & 63;
    const int pix = blockIdx.x * 4 + wv;
    const int b = pix / HW, hw = pix % HW, h = hw / W, w = hw % W;
    const float* xb = x + (long)b * C * HW;

    float v[NL];
    float s = 0.f, s2 = 0.f;
    #pragma unroll
    for (int t = 0; t < NL; ++t) {
        int i = t * 64 + lane;
        float val = 0.f;
        if (i < IN) {
            int ch = i / 9, r = i - ch * 9;
            int y = h + r / 3 - 1, xx = w + r % 3 - 1;
            if (y >= 0 && y < H && xx >= 0 && xx < W)
                val = xb[ch * HW + y * W + xx];
        }
        v[t] = val; s += val; s2 += val * val;
    }
    #pragma unroll
    for (int off = 32; off > 0; off >>= 1) {
        s  += __shfl_down(s,  off, 64);
        s2 += __shfl_down(s2, off, 64);
    }
    s = __shfl(s, 0, 64); s2 = __shfl(s2, 0, 64);
    float mean = s / IN;
    float istd = rsqrtf(s2 / IN - mean * mean + 1e-5f);

    #pragma unroll
    for (int t = 0; t < NL; ++t) {
        int i = t * 64 + lane;
        if (i < IN) {
            float val = v[t];
            float pnv = (val - mean) * istd * lnw[i] + lnb[i];
            pn[(long)pix * IN + i] = (half_t)(pnv * RBF_SCALE);
            sp[(long)pix * IN + i] = (half_t)(val / (1.f + __expf(-val)));
        }
    }
}

// ---- fp32 weights -> fp16 packed [KIT][OUT][64], XOR swizzle pre-applied ----
// packed[(it*OUT + o)*64 + s] = W[o][it*64 + ((s>>3)^(o&7))*8 + (s&7)]
// where W[o][k]: k = j*IN + i, j<8 -> Ws, j==8 -> Wb, else 0 (K padding).
template<int IN, int OUT, int KPAD>
__global__ __launch_bounds__(256)
void conv_w(const float* __restrict__ Ws, const float* __restrict__ Wb,
            half_t* __restrict__ Wt)
{
    int idx = blockIdx.x * 256 + threadIdx.x;
    if (idx >= OUT * KPAD) return;
    int s = idx & 63;
    int t = idx >> 6;
    int o = t % OUT;
    int it = t / OUT;
    int k = it * 64 + (((s >> 3) ^ (o & 7)) << 3) + (s & 7);
    float v = 0.f;
    if (k < IN * 9) {
        int j = k / IN, i = k - j * IN;
        v = (j < 8) ? Ws[(long)o * IN * 8 + i * 8 + j] : Wb[(long)o * IN + i];
    }
    Wt[idx] = (half_t)v;
}

// ---- fused A-gen + MFMA GEMM ----
// block: 64 pixels x OUT outputs (grid.y == 1); wave wv: NB*16 outputs x 64 px.
// B staged via global_load_lds from packed weights (linear LDS dest; swizzle
// pre-applied in global layout). A staged via registers with swizzled ds_write.
// LDS XOR swizzle: 16B unit u stored at u ^ (row & 7), row stride 64 halfs.
// Split-K partials: plain stores to out + z * npix * OUT (no atomics).
template<int IN, int OUT, int HW, int NB, int SPLIT>
__global__ __launch_bounds__(256)
void kan_gemm(const half_t* __restrict__ pn, const half_t* __restrict__ sp,
              const half_t* __restrict__ Wt, float* __restrict__ out)
{
    const int K = IN * 9, KPAD = (K + 63) & ~63, KIT = KPAD / 64;

    __shared__ half_t As[64 * 64];
    __shared__ half_t Bs[NB * 64 * 64];

    const int tid = threadIdx.x;
    const int row = tid >> 2, q = tid & 3;
    const int pix = blockIdx.x * 64 + row;
    const half_t* pnrow = pn + (long)pix * IN;
    const half_t* sprow = sp + (long)pix * IN;

    const int wv = tid >> 6, lane = tid & 63;
    const int lr = lane & 15, lq = lane >> 4;
    const int u0 = (2 * q) ^ (row & 7);         // swizzled 16B units (A stage)
    const int u1 = (2 * q + 1) ^ (row & 7);

    floatx4 acc[NB][4] = {};

    const int it0 = (blockIdx.z * KIT) / SPLIT;
    const int it1 = ((blockIdx.z + 1) * KIT) / SPLIT;

    for (int it = it0; it < it1; ++it) {
        const int k0 = it * 64;
        __syncthreads();   // previous MFMA reads done

        // ---- stage B: NB*2 x 1KB global_load_lds per wave (linear copy) ----
        {
            const half_t* ws = Wt + (long)it * OUT * 64 + wv * (NB * 2 * 512);
            #pragma unroll
            for (int c = 0; c < NB * 2; ++c) {
                __builtin_amdgcn_global_load_lds(
                    (const __attribute__((address_space(1))) void*)(ws + c * 512 + lane * 8),
                    (__attribute__((address_space(3))) void*)(&Bs[wv * (NB * 2 * 512) + c * 512]),
                    16, 0, 0);
            }
        }

        // ---- stage A: 16 elements, uniform j per 16-chunk (IN % 16 == 0) ----
        {
            int cs = k0 + q * 16;
            int j = cs / IN;
            half8 a0, a1;
            if (j < 8) {
                int i0 = cs - j * IN;
                float gj = RBF_SCALE * (-2.f + j * (4.f / 7.f));
                half8 p0 = *(const half8*)(pnrow + i0);
                half8 p1 = *(const half8*)(pnrow + i0 + 8);
                #pragma unroll
                for (int kk = 0; kk < 8; ++kk) {
                    float v0 = (float)p0[kk] - gj;
                    a0[kk] = (half_t)__builtin_amdgcn_exp2f(-(v0 * v0));
                    float v1 = (float)p1[kk] - gj;
                    a1[kk] = (half_t)__builtin_amdgcn_exp2f(-(v1 * v1));
                }
            } else if (j == 8) {
                int i0 = cs - 8 * IN;
                a0 = *(const half8*)(sprow + i0);
                a1 = *(const half8*)(sprow + i0 + 8);
            } else {
                a0 = half8{}; a1 = half8{};
            }
            *(half8*)&As[row * 64 + u0 * 8] = a0;
            *(half8*)&As[row * 64 + u1 * 8] = a1;
        }
        __syncthreads();

        // ---- MFMA ----
        #pragma unroll
        for (int ks = 0; ks < 2; ++ks) {
            half8 af[4], bf[NB];
            #pragma unroll
            for (int mf = 0; mf < 4; ++mf) {
                int r = mf * 16 + lr;
                af[mf] = *(const half8*)&As[r * 64 + (((ks * 4 + lq) ^ (r & 7)) * 8)];
            }
            #pragma unroll
            for (int nb = 0; nb < NB; ++nb) {
                int r = wv * NB * 16 + nb * 16 + lr;
                bf[nb] = *(const half8*)&Bs[r * 64 + (((ks * 4 + lq) ^ (r & 7)) * 8)];
            }
            #pragma unroll
            for (int nb = 0; nb < NB; ++nb)
                #pragma unroll
                for (int mf = 0; mf < 4; ++mf)
                    acc[nb][mf] = __builtin_amdgcn_mfma_f32_16x16x32_f16(
                        bf[nb], af[mf], acc[nb][mf], 0, 0, 0);
        }
    }

    // ---- epilogue: plain stores into z-partial slab ----
    const long zoff = (long)blockIdx.z * ((long)gridDim.x * 64) * OUT;
    #pragma unroll
    for (int nb = 0; nb < NB; ++nb)
    #pragma unroll
    for (int mf = 0; mf < 4; ++mf)
    #pragma unroll
    for (int reg = 0; reg < 4; ++reg) {
        int o  = wv * NB * 16 + nb * 16 + lq * 4 + reg;
        int p2 = blockIdx.x * 64 + mf * 16 + lr;
        int b2 = p2 / HW, hw2 = p2 % HW;
        out[zoff + ((long)b2 * OUT + o) * HW + hw2] = acc[nb][mf][reg];
    }
}

// ---- BatchNorm batch-stats over summed z-partials (bias folded in) ----
__launch_bounds__(256)
__global__ void bn_stats(const float* __restrict__ h, const float* __restrict__ bias,
                         int C, int HW, int B, int nz, float* __restrict__ sums)
{
    int c = blockIdx.y;
    float bbc = bias[c];
    long zstride = (long)B * C * HW;
    int total = B * HW;
    float s = 0.f, s2 = 0.f;
    for (int idx = blockIdx.x * 256 + threadIdx.x; idx < total; idx += 256 * gridDim.x) {
        int b = idx / HW, r = idx % HW;
        long base = ((long)b * C + c) * HW + r;
        float v = bbc;
        for (int z = 0; z < nz; ++z) v += h[z * zstride + base];
        s += v; s2 += v * v;
    }
    for (int off = 32; off > 0; off >>= 1) {
        s  += __shfl_down(s,  off, 64);
        s2 += __shfl_down(s2, off, 64);
    }
    __shared__ float rs[4], rs2[4];
    int lane = threadIdx.x & 63, wid = threadIdx.x >> 6;
    if (lane == 0) { rs[wid] = s; rs2[wid] = s2; }
    __syncthreads();
    if (threadIdx.x == 0) {
        atomicAdd(&sums[c],     rs[0] + rs[1] + rs[2] + rs[3]);
        atomicAdd(&sums[C + c], rs2[0] + rs2[1] + rs2[2] + rs2[3]);
    }
}

__launch_bounds__(256)
__global__ void bn_relu_pool(const float* __restrict__ h, const float* __restrict__ sums,
                             const float* __restrict__ bias,
                             const float* __restrict__ gamma, const float* __restrict__ beta,
                             float* __restrict__ out, int B, int C, int H, int W, int nz)
{
    int Ho = H / 2, Wo = W / 2;
    long total = (long)B * C * Ho * Wo;
    long idx = (long)blockIdx.x * 256 + threadIdx.x;
    if (idx >= total) return;
    int pw = idx % Wo; long t = idx / Wo;
    int ph = t % Ho; t /= Ho;
    int c = t % C; int b = (int)(t / C);

    float M = (float)B * H * W;
    float mean = sums[c] / M;
    float var  = sums[C + c] / M - mean * mean;
    float scale = gamma[c] * rsqrtf(var + 1e-5f);
    float shift = beta[c] - mean * scale + bias[c] * scale;  // fold conv bias

    long zstride = (long)B * C * H * W;
    const float* hp = h + ((long)b * C + c) * H * W;
    float m = 0.f;  // post-relu >= 0
    #pragma unroll
    for (int i = 0; i < 2; ++i)
        #pragma unroll
        for (int j = 0; j < 2; ++j) {
            long off = (2 * ph + i) * W + 2 * pw + j;
            float v = 0.f;
            for (int z = 0; z < nz; ++z) v += hp[z * zstride + off];
            v = v * scale + shift;
            m = fmaxf(m, v);
        }
    out[idx] = m;
}

extern "C" void kernel_launch(void* const* d_in, const int* in_sizes, int n_in,
                              void* d_out, int out_size, void* d_ws, size_t ws_size,
                              hipStream_t stream) {
    const float* x     = (const float*)d_in[0];
    const float* ln_w1 = (const float*)d_in[1];  const float* ln_b1 = (const float*)d_in[2];
    const float* Wb1   = (const float*)d_in[3];  const float* bb1   = (const float*)d_in[4];
    const float* Ws1   = (const float*)d_in[5];  const float* g1    = (const float*)d_in[6];
    const float* be1   = (const float*)d_in[7];
    const float* ln_w2 = (const float*)d_in[8];  const float* ln_b2 = (const float*)d_in[9];
    const float* Wb2   = (const float*)d_in[10]; const float* bb2   = (const float*)d_in[11];
    const float* Ws2   = (const float*)d_in[12]; const float* g2    = (const float*)d_in[13];
    const float* be2   = (const float*)d_in[14];
    const float* ln_w3 = (const float*)d_in[15]; const float* ln_b3 = (const float*)d_in[16];
    const float* Wb3   = (const float*)d_in[17]; const float* bb3   = (const float*)d_in[18];
    const float* Ws3   = (const float*)d_in[19]; const float* g3    = (const float*)d_in[20];
    const float* be3   = (const float*)d_in[21];

    const int B = 32;
    char* ws = (char*)d_ws;
    float*  convbuf = (float*)(ws + 0);              // 33,554,432 (also z-partials L2/L3)
    float*  poolbuf = (float*)(ws + 33554432);       //  8,388,608
    float*  stats1  = (float*)(ws + 41943040);       //  2048 x3
    float*  stats2  = (float*)(ws + 41945088);
    float*  stats3  = (float*)(ws + 41947136);
    half_t* wt1     = (half_t*)(ws + 41949184);      //   172,032  (21 x 64 x 64)
    half_t* wt2     = (half_t*)(ws + 42121216);      // 1,327,104  (81 x 128 x 64)
    half_t* wt3     = (half_t*)(ws + 43448320);      // 5,308,416  (162 x 256 x 64)
    half_t* pnbuf   = (half_t*)(ws + 48756736);      // 37,748,736 (max 131072x144)
    half_t* spbuf   = (half_t*)(ws + 86505472);      // 37,748,736
    // total: 124,254,208 B

    hipMemsetAsync(stats1, 0, 6144, stream);

    conv_w<144, 64, 1344><<<(64 * 1344 + 255) / 256, 256, 0, stream>>>(Ws1, Wb1, wt1);
    conv_w<576, 128, 5184><<<(128 * 5184 + 255) / 256, 256, 0, stream>>>(Ws2, Wb2, wt2);
    conv_w<1152, 256, 10368><<<(256 * 10368 + 255) / 256, 256, 0, stream>>>(Ws3, Wb3, wt3);

    // ---------------- layer 1: C=16, H=W=64, OUT=64, NB=1, SPLIT=1 ----------
    {
        const int H = 64, W = 64, OUT = 64;
        int npix = B * H * W;                    // 131072
        ln_prep<16, H, W><<<npix / 4, 256, 0, stream>>>(x, ln_w1, ln_b1, pnbuf, spbuf);
        kan_gemm<144, OUT, H * W, 1, 1><<<dim3(npix / 64, 1, 1), 256, 0, stream>>>(
            pnbuf, spbuf, wt1, convbuf);
        bn_stats<<<dim3(64, OUT), 256, 0, stream>>>(convbuf, bb1, OUT, H * W, B, 1, stats1);
        long tot = (long)B * OUT * (H / 2) * (W / 2);
        bn_relu_pool<<<(tot + 255) / 256, 256, 0, stream>>>(
            convbuf, stats1, bb1, g1, be1, poolbuf, B, OUT, H, W, 1);
    }
    // ---------------- layer 2: C=64, H=W=32, OUT=128, NB=2, SPLIT=2 ---------
    {
        const int H = 32, W = 32, OUT = 128;
        int npix = B * H * W;                    // 32768
        ln_prep<64, H, W><<<npix / 4, 256, 0, stream>>>(poolbuf, ln_w2, ln_b2, pnbuf, spbuf);
        kan_gemm<576, OUT, H * W, 2, 2><<<dim3(npix / 64, 1, 2), 256, 0, stream>>>(
            pnbuf, spbuf, wt2, convbuf);           // 2 x 16.8 MB partials in convbuf
        bn_stats<<<dim3(16, OUT), 256, 0, stream>>>(convbuf, bb2, OUT, H * W, B, 2, stats2);
        long tot = (long)B * OUT * (H / 2) * (W / 2);
        bn_relu_pool<<<(tot + 255) / 256, 256, 0, stream>>>(
            convbuf, stats2, bb2, g2, be2, poolbuf, B, OUT, H, W, 2);
    }
    // ---------------- layer 3: C=128, H=W=16, OUT=256, NB=4, SPLIT=4 --------
    {
        const int H = 16, W = 16, OUT = 256;
        int npix = B * H * W;                    // 8192
        ln_prep<128, H, W><<<npix / 4, 256, 0, stream>>>(poolbuf, ln_w3, ln_b3, pnbuf, spbuf);
        kan_gemm<1152, OUT, H * W, 4, 4><<<dim3(npix / 64, 1, 4), 256, 0, stream>>>(
            pnbuf, spbuf, wt3, convbuf);           // 4 x 8.4 MB partials in convbuf
        bn_stats<<<dim3(8, OUT), 256, 0, stream>>>(convbuf, bb3, OUT, H * W, B, 4, stats3);
        long tot = (long)B * OUT * (H / 2) * (W / 2);  // 524288 == out_size
        bn_relu_pool<<<(tot + 255) / 256, 256, 0, stream>>>(
            convbuf, stats3, bb3, g3, be3, (float*)d_out, B, OUT, H, W, 4);
    }
}